// Round 1
// baseline (112139.807 us; speedup 1.0000x reference)
//
#include <hip/hip_runtime.h>
#include <hip/hip_fp16.h>

// LSTM_54537494725306: 2-layer LSTM, T=2048, D=512, H=2048, OUT=64, fp32 in/out.
// R3: register/LDS-resident weights. R2 streamed 109.3 MB of fp16 weights per
// step; rocprof showed FETCH 53.5 MB/step at a pinned 2.07 TB/s fill BW =
// 25.8 us/step (latency-bound, VALUBusy 9%). Now each wave holds its 4 gate-rows
// of Wih1/Wih2/Whh2 + Whh1(g,o) packed fp16 in 176 VGPRs; Whh1(i,f) lives in
// 64 KB LDS per CU. Weights are fetched from HBM exactly once. Per-step traffic
// is only x/h vectors (L1-resident) + Wlin for the 64 y-waves.
// Math is bit-identical to R2 (fp16 weights -> f32 cvt -> f32 fmaf, same order).

#define T_STEPS 2048
#define DIM_D   512
#define DIM_H   2048
#define DIM_OUT 64
#define NWG     256
#define NTHR    512

#define N_WIH1 (4 * DIM_H * DIM_D)   //  4,194,304
#define N_WHH1 (4 * DIM_H * DIM_H)   // 16,777,216
#define N_WIH2 (4 * DIM_H * DIM_H)
#define N_WHH2 (4 * DIM_H * DIM_H)
#define N_WLIN (DIM_OUT * DIM_H)     //    131,072
#define WS_WEIGHT_OFF 65536

__device__ __forceinline__ float sigf(float x)   { return 1.0f / (1.0f + __expf(-x)); }
__device__ __forceinline__ float tanh_f(float x) { return 1.0f - 2.0f / (__expf(2.0f * x) + 1.0f); }

__device__ __forceinline__ float wave_reduce(float v) {
#pragma unroll
    for (int off = 32; off > 0; off >>= 1) v += __shfl_xor(v, off, 64);
    return v;
}

struct F8 { float4 a, b; };

__device__ __forceinline__ F8 load8(const float* __restrict__ p, int e) {
    F8 r;
    const float4* q = (const float4*)(p + e);
    r.a = q[0]; r.b = q[1];
    return r;
}

__device__ __forceinline__ F8 cvt8(uint4 u) {
    float2 f0 = __half22float2(*(__half2*)&u.x);
    float2 f1 = __half22float2(*(__half2*)&u.y);
    float2 f2 = __half22float2(*(__half2*)&u.z);
    float2 f3 = __half22float2(*(__half2*)&u.w);
    F8 r;
    r.a = make_float4(f0.x, f0.y, f1.x, f1.y);
    r.b = make_float4(f2.x, f2.y, f3.x, f3.y);
    return r;
}

__device__ __forceinline__ F8 load8(const __half* __restrict__ p, int e) {
    uint4 u = *(const uint4*)(p + e);
    return cvt8(u);
}

__device__ __forceinline__ float dot8(const F8& v, const F8& w, float acc) {
    acc = fmaf(v.a.x, w.a.x, acc); acc = fmaf(v.a.y, w.a.y, acc);
    acc = fmaf(v.a.z, w.a.z, acc); acc = fmaf(v.a.w, w.a.w, acc);
    acc = fmaf(v.b.x, w.b.x, acc); acc = fmaf(v.b.y, w.b.y, acc);
    acc = fmaf(v.b.z, w.b.z, acc); acc = fmaf(v.b.w, w.b.w, acc);
    return acc;
}

// 4-row dot over K elements (fallback streaming path only).
template<int K, typename WT>
__device__ __forceinline__ void dot4(const float* __restrict__ v,
                                     const WT* __restrict__ w0, const WT* __restrict__ w1,
                                     const WT* __restrict__ w2, const WT* __restrict__ w3,
                                     int lane, float& a0, float& a1, float& a2, float& a3) {
#pragma unroll
    for (int i = 0; i < K / 512; ++i) {
        const int e = (lane + 64 * i) * 8;
        const F8 vv = load8(v, e);
        a0 = dot8(vv, load8(w0, e), a0);
        a1 = dot8(vv, load8(w1, e), a1);
        a2 = dot8(vv, load8(w2, e), a2);
        a3 = dot8(vv, load8(w3, e), a3);
    }
}

// Two-level sense-free barrier. Generation counter lives in a register (all
// threads hold the same value), freeing the LDS word so the 64 KB weight
// arena fits exactly.
__device__ __forceinline__ void grid_barrier(int* bar, int wg, int g) {
    __syncthreads();
    if (threadIdx.x == 0) {
        const int grp = wg >> 5;
        int a = __hip_atomic_fetch_add(&bar[grp * 32], 1, __ATOMIC_ACQ_REL, __HIP_MEMORY_SCOPE_AGENT);
        if (a == 31) {
            int r = __hip_atomic_fetch_add(&bar[256], 1, __ATOMIC_ACQ_REL, __HIP_MEMORY_SCOPE_AGENT);
            if (r == 7) {
#pragma unroll
                for (int i = 0; i < 8; ++i)
                    __hip_atomic_store(&bar[i * 32], 0, __ATOMIC_RELAXED, __HIP_MEMORY_SCOPE_AGENT);
                __hip_atomic_store(&bar[256], 0, __ATOMIC_RELAXED, __HIP_MEMORY_SCOPE_AGENT);
                __hip_atomic_store(&bar[288], g + 1, __ATOMIC_RELEASE, __HIP_MEMORY_SCOPE_AGENT);
            }
        }
        while (__hip_atomic_load(&bar[288], __ATOMIC_RELAXED, __HIP_MEMORY_SCOPE_AGENT) <= g) {
            __builtin_amdgcn_s_sleep(2);
        }
        __builtin_amdgcn_fence(__ATOMIC_ACQUIRE, "agent");
    }
    __syncthreads();
}

__global__ void lstm_init(int* bar, float* h1buf, float* h2buf) {
    int i = threadIdx.x + blockIdx.x * blockDim.x;
    if (i < 512) bar[i] = 0;
    if (i < 2 * DIM_H) { h1buf[i] = 0.0f; h2buf[i] = 0.0f; }
}

// fp32 -> fp16 (RNE), 4 elements/thread.
__global__ void convert_f16(const float* __restrict__ src, __half* __restrict__ dst, int n4) {
    int i = threadIdx.x + blockIdx.x * blockDim.x;
    if (i < n4) {
        float4 f = ((const float4*)src)[i];
        __half2 h01 = __floats2half2_rn(f.x, f.y);
        __half2 h23 = __floats2half2_rn(f.z, f.w);
        uint2 o;
        o.x = *(unsigned int*)&h01;
        o.y = *(unsigned int*)&h23;
        ((uint2*)dst)[i] = o;
    }
}

// ---------------------------------------------------------------------------
// Main path: weights chip-resident.
//   per wave (unit u = wg*8+wave, rows u, H+u, 2H+u, 3H+u):
//     VGPR (packed fp16, uint4 = 8 elems):
//       wI1[4]      Wih1 rows (K=512)          16 regs
//       wH1g[4]     Whh1 row 2H+u (g gate)     16 regs
//       wH1o[4]     Whh1 row 3H+u (o gate)     16 regs
//       wI2[4][4]   Wih2 rows (K=2048)         64 regs
//       wH2[4][4]   Whh2 rows (K=2048)         64 regs   -> 176 regs of weights
//     LDS: Whh1 rows u (i gate), H+u (f gate): 8 waves * 2 * 2048 fp16 = 64 KB
// ---------------------------------------------------------------------------
__global__ __launch_bounds__(NTHR, 2) void lstm_resident(
    const float* __restrict__ x,
    const __half* __restrict__ Wih1, const __half* __restrict__ Whh1,
    const float* __restrict__ bih1, const float* __restrict__ bhh1,
    const __half* __restrict__ Wih2, const __half* __restrict__ Whh2,
    const float* __restrict__ bih2, const float* __restrict__ bhh2,
    const __half* __restrict__ Wlin, const float* __restrict__ blin,
    float* __restrict__ out,
    int* bar, float* h1buf, float* h2buf)
{
    const int wg   = blockIdx.x;
    const int wave = threadIdx.x >> 6;
    const int lane = threadIdx.x & 63;
    const int unit = wg * 8 + wave;

    __shared__ uint4 ldsW[8][2][DIM_H / 8];   // exactly 65536 bytes

    const int r0 = unit, r1 = DIM_H + unit, r2 = 2 * DIM_H + unit, r3 = 3 * DIM_H + unit;

    const float b1_0 = bih1[r0] + bhh1[r0];
    const float b1_1 = bih1[r1] + bhh1[r1];
    const float b1_2 = bih1[r2] + bhh1[r2];
    const float b1_3 = bih1[r3] + bhh1[r3];
    const float b2_0 = bih2[r0] + bhh2[r0];
    const float b2_1 = bih2[r1] + bhh2[r1];
    const float b2_2 = bih2[r2] + bhh2[r2];
    const float b2_3 = bih2[r3] + bhh2[r3];

    // ---------------- one-time weight residency ----------------
    uint4 wI1[4];
    uint4 wH1g[4], wH1o[4];
    uint4 wI2[4][4], wH2[4][4];
    {
        const int rr0 = r0, rr1 = r1, rr2 = r2, rr3 = r3;
        {
            wI1[0] = ((const uint4*)(Wih1 + (size_t)rr0 * DIM_D))[lane];
            wI1[1] = ((const uint4*)(Wih1 + (size_t)rr1 * DIM_D))[lane];
            wI1[2] = ((const uint4*)(Wih1 + (size_t)rr2 * DIM_D))[lane];
            wI1[3] = ((const uint4*)(Wih1 + (size_t)rr3 * DIM_D))[lane];
        }
        const uint4* pg = (const uint4*)(Whh1 + (size_t)rr2 * DIM_H);
        const uint4* po = (const uint4*)(Whh1 + (size_t)rr3 * DIM_H);
#pragma unroll
        for (int i = 0; i < 4; ++i) {
            wH1g[i] = pg[lane + 64 * i];
            wH1o[i] = po[lane + 64 * i];
        }
        const uint4* pi0 = (const uint4*)(Wih2 + (size_t)rr0 * DIM_H);
        const uint4* pi1 = (const uint4*)(Wih2 + (size_t)rr1 * DIM_H);
        const uint4* pi2 = (const uint4*)(Wih2 + (size_t)rr2 * DIM_H);
        const uint4* pi3 = (const uint4*)(Wih2 + (size_t)rr3 * DIM_H);
        const uint4* ph0 = (const uint4*)(Whh2 + (size_t)rr0 * DIM_H);
        const uint4* ph1 = (const uint4*)(Whh2 + (size_t)rr1 * DIM_H);
        const uint4* ph2 = (const uint4*)(Whh2 + (size_t)rr2 * DIM_H);
        const uint4* ph3 = (const uint4*)(Whh2 + (size_t)rr3 * DIM_H);
#pragma unroll
        for (int i = 0; i < 4; ++i) {
            const int t = lane + 64 * i;
            wI2[0][i] = pi0[t]; wI2[1][i] = pi1[t];
            wI2[2][i] = pi2[t]; wI2[3][i] = pi3[t];
            wH2[0][i] = ph0[t]; wH2[1][i] = ph1[t];
            wH2[2][i] = ph2[t]; wH2[3][i] = ph3[t];
        }
        const uint4* qi = (const uint4*)(Whh1 + (size_t)rr0 * DIM_H);
        const uint4* qf = (const uint4*)(Whh1 + (size_t)rr1 * DIM_H);
#pragma unroll
        for (int i = 0; i < 4; ++i) {
            const int t = lane + 64 * i;
            ldsW[wave][0][t] = qi[t];
            ldsW[wave][1][t] = qf[t];
        }
    }
    __syncthreads();

    const bool  do_y = (wg < DIM_OUT) && (wave == 0);
    const float by   = (wg < DIM_OUT) ? blin[wg] : 0.0f;
    const __half* wy = Wlin + (size_t)(wg < DIM_OUT ? wg : 0) * DIM_H;

    float c1 = 0.0f, c2 = 0.0f;

    for (int p = 0; p < T_STEPS + 2; ++p) {
        const float* h1_prev  = h1buf + (size_t)((p + 1) & 1) * DIM_H;  // h1[p-1]
        float*       h1_cur   = h1buf + (size_t)(p & 1) * DIM_H;        // h1[p]
        const float* h2_prev2 = h2buf + (size_t)(p & 1) * DIM_H;        // h2[p-2]
        float*       h2_cur   = h2buf + (size_t)((p + 1) & 1) * DIM_H;  // h2[p-1]

        // ---------------- layer 1, step p ----------------
        if (p < T_STEPS) {
            float a0 = 0.f, a1 = 0.f, a2 = 0.f, a3 = 0.f;
            const F8 xv = load8(x + (size_t)p * DIM_D, lane * 8);
            a0 = dot8(xv, cvt8(wI1[0]), a0);
            a1 = dot8(xv, cvt8(wI1[1]), a1);
            a2 = dot8(xv, cvt8(wI1[2]), a2);
            a3 = dot8(xv, cvt8(wI1[3]), a3);
#pragma unroll
            for (int i = 0; i < 4; ++i) {
                const int t = lane + 64 * i;
                const F8 hv = load8(h1_prev, t * 8);
                a0 = dot8(hv, cvt8(ldsW[wave][0][t]), a0);
                a1 = dot8(hv, cvt8(ldsW[wave][1][t]), a1);
                a2 = dot8(hv, cvt8(wH1g[i]), a2);
                a3 = dot8(hv, cvt8(wH1o[i]), a3);
            }
            a0 = wave_reduce(a0); a1 = wave_reduce(a1);
            a2 = wave_reduce(a2); a3 = wave_reduce(a3);
            const float gi = sigf(a0 + b1_0);
            const float gf = sigf(a1 + b1_1);
            const float gg = tanh_f(a2 + b1_2);
            const float go = sigf(a3 + b1_3);
            c1 = fmaf(gf, c1, gi * gg);
            if (lane == 0) h1_cur[unit] = go * tanh_f(c1);
        }

        // ---------------- layer 2, step p-1 ----------------
        if (p >= 1 && p <= T_STEPS) {
            float a0 = 0.f, a1 = 0.f, a2 = 0.f, a3 = 0.f;
#pragma unroll
            for (int i = 0; i < 4; ++i) {
                const int t = lane + 64 * i;
                const F8 v = load8(h1_prev, t * 8);
                a0 = dot8(v, cvt8(wI2[0][i]), a0);
                a1 = dot8(v, cvt8(wI2[1][i]), a1);
                a2 = dot8(v, cvt8(wI2[2][i]), a2);
                a3 = dot8(v, cvt8(wI2[3][i]), a3);
            }
#pragma unroll
            for (int i = 0; i < 4; ++i) {
                const int t = lane + 64 * i;
                const F8 v = load8(h2_prev2, t * 8);
                a0 = dot8(v, cvt8(wH2[0][i]), a0);
                a1 = dot8(v, cvt8(wH2[1][i]), a1);
                a2 = dot8(v, cvt8(wH2[2][i]), a2);
                a3 = dot8(v, cvt8(wH2[3][i]), a3);
            }
            a0 = wave_reduce(a0); a1 = wave_reduce(a1);
            a2 = wave_reduce(a2); a3 = wave_reduce(a3);
            const float gi = sigf(a0 + b2_0);
            const float gf = sigf(a1 + b2_1);
            const float gg = tanh_f(a2 + b2_2);
            const float go = sigf(a3 + b2_3);
            c2 = fmaf(gf, c2, gi * gg);
            if (lane == 0) h2_cur[unit] = go * tanh_f(c2);
        }

        // ---------------- y, step p-2 ----------------
        if (do_y && p >= 2) {
            float a = 0.f;
#pragma unroll
            for (int i = 0; i < DIM_H / 512; ++i) {
                const int e = (lane + 64 * i) * 8;
                a = dot8(load8(h2_prev2, e), load8(wy, e), a);
            }
            a = wave_reduce(a);
            if (lane == 0) out[(size_t)(p - 2) * DIM_OUT + wg] = a + by;
        }

        grid_barrier(bar, wg, p);
    }
}

// ---------------------------------------------------------------------------
// Fallback: R2-style fp32 weight streaming (used only if workspace too small).
// ---------------------------------------------------------------------------
__global__ __launch_bounds__(NTHR, 2) void lstm_stream_f32(
    const float* __restrict__ x,
    const float* __restrict__ Wih1, const float* __restrict__ Whh1,
    const float* __restrict__ bih1, const float* __restrict__ bhh1,
    const float* __restrict__ Wih2, const float* __restrict__ Whh2,
    const float* __restrict__ bih2, const float* __restrict__ bhh2,
    const float* __restrict__ Wlin, const float* __restrict__ blin,
    float* __restrict__ out,
    int* bar, float* h1buf, float* h2buf)
{
    const int wg   = blockIdx.x;
    const int wave = threadIdx.x >> 6;
    const int lane = threadIdx.x & 63;
    const int unit = wg * 8 + wave;

    const int r0 = unit, r1 = DIM_H + unit, r2 = 2 * DIM_H + unit, r3 = 3 * DIM_H + unit;
    const float b1_0 = bih1[r0] + bhh1[r0];
    const float b1_1 = bih1[r1] + bhh1[r1];
    const float b1_2 = bih1[r2] + bhh1[r2];
    const float b1_3 = bih1[r3] + bhh1[r3];
    const float b2_0 = bih2[r0] + bhh2[r0];
    const float b2_1 = bih2[r1] + bhh2[r1];
    const float b2_2 = bih2[r2] + bhh2[r2];
    const float b2_3 = bih2[r3] + bhh2[r3];

    const float* wi1_0 = Wih1 + (size_t)r0 * DIM_D;
    const float* wi1_1 = Wih1 + (size_t)r1 * DIM_D;
    const float* wi1_2 = Wih1 + (size_t)r2 * DIM_D;
    const float* wi1_3 = Wih1 + (size_t)r3 * DIM_D;
    const float* wh1_0 = Whh1 + (size_t)r0 * DIM_H;
    const float* wh1_1 = Whh1 + (size_t)r1 * DIM_H;
    const float* wh1_2 = Whh1 + (size_t)r2 * DIM_H;
    const float* wh1_3 = Whh1 + (size_t)r3 * DIM_H;
    const float* wi2_0 = Wih2 + (size_t)r0 * DIM_H;
    const float* wi2_1 = Wih2 + (size_t)r1 * DIM_H;
    const float* wi2_2 = Wih2 + (size_t)r2 * DIM_H;
    const float* wi2_3 = Wih2 + (size_t)r3 * DIM_H;
    const float* wh2_0 = Whh2 + (size_t)r0 * DIM_H;
    const float* wh2_1 = Whh2 + (size_t)r1 * DIM_H;
    const float* wh2_2 = Whh2 + (size_t)r2 * DIM_H;
    const float* wh2_3 = Whh2 + (size_t)r3 * DIM_H;

    const bool  do_y = (wg < DIM_OUT) && (wave == 0);
    const float by   = (wg < DIM_OUT) ? blin[wg] : 0.0f;
    const float* wy  = Wlin + (size_t)(wg < DIM_OUT ? wg : 0) * DIM_H;

    float c1 = 0.0f, c2 = 0.0f;

    for (int p = 0; p < T_STEPS + 2; ++p) {
        const float* h1_prev  = h1buf + (size_t)((p + 1) & 1) * DIM_H;
        float*       h1_cur   = h1buf + (size_t)(p & 1) * DIM_H;
        const float* h2_prev2 = h2buf + (size_t)(p & 1) * DIM_H;
        float*       h2_cur   = h2buf + (size_t)((p + 1) & 1) * DIM_H;

        if (p < T_STEPS) {
            float a0 = 0.f, a1 = 0.f, a2 = 0.f, a3 = 0.f;
            dot4<DIM_D>(x + (size_t)p * DIM_D, wi1_0, wi1_1, wi1_2, wi1_3, lane, a0, a1, a2, a3);
            dot4<DIM_H>(h1_prev, wh1_0, wh1_1, wh1_2, wh1_3, lane, a0, a1, a2, a3);
            a0 = wave_reduce(a0); a1 = wave_reduce(a1);
            a2 = wave_reduce(a2); a3 = wave_reduce(a3);
            const float gi = sigf(a0 + b1_0);
            const float gf = sigf(a1 + b1_1);
            const float gg = tanh_f(a2 + b1_2);
            const float go = sigf(a3 + b1_3);
            c1 = fmaf(gf, c1, gi * gg);
            if (lane == 0) h1_cur[unit] = go * tanh_f(c1);
        }

        if (p >= 1 && p <= T_STEPS) {
            float a0 = 0.f, a1 = 0.f, a2 = 0.f, a3 = 0.f;
            dot4<DIM_H>(h1_prev,  wi2_0, wi2_1, wi2_2, wi2_3, lane, a0, a1, a2, a3);
            dot4<DIM_H>(h2_prev2, wh2_0, wh2_1, wh2_2, wh2_3, lane, a0, a1, a2, a3);
            a0 = wave_reduce(a0); a1 = wave_reduce(a1);
            a2 = wave_reduce(a2); a3 = wave_reduce(a3);
            const float gi = sigf(a0 + b2_0);
            const float gf = sigf(a1 + b2_1);
            const float gg = tanh_f(a2 + b2_2);
            const float go = sigf(a3 + b2_3);
            c2 = fmaf(gf, c2, gi * gg);
            if (lane == 0) h2_cur[unit] = go * tanh_f(c2);
        }

        if (do_y && p >= 2) {
            float a = 0.f;
#pragma unroll
            for (int i = 0; i < DIM_H / 512; ++i) {
                const int e = (lane + 64 * i) * 8;
                a = dot8(load8(h2_prev2, e), load8(wy, e), a);
            }
            a = wave_reduce(a);
            if (lane == 0) out[(size_t)(p - 2) * DIM_OUT + wg] = a + by;
        }

        grid_barrier(bar, wg, p);
    }
}

extern "C" void kernel_launch(void* const* d_in, const int* in_sizes, int n_in,
                              void* d_out, int out_size, void* d_ws, size_t ws_size,
                              hipStream_t stream) {
    const float* x    = (const float*)d_in[0];
    const float* Wih1 = (const float*)d_in[1];
    const float* Whh1 = (const float*)d_in[2];
    const float* bih1 = (const float*)d_in[3];
    const float* bhh1 = (const float*)d_in[4];
    const float* Wih2 = (const float*)d_in[5];
    const float* Whh2 = (const float*)d_in[6];
    const float* bih2 = (const float*)d_in[7];
    const float* bhh2 = (const float*)d_in[8];
    const float* Wlin = (const float*)d_in[9];
    const float* blin = (const float*)d_in[10];
    float* out = (float*)d_out;

    int*   bar   = (int*)d_ws;
    float* h1buf = (float*)((char*)d_ws + 4096);
    float* h2buf = h1buf + 2 * DIM_H;

    lstm_init<<<16, 256, 0, stream>>>(bar, h1buf, h2buf);

    const size_t nweights = (size_t)N_WIH1 + N_WHH1 + N_WIH2 + N_WHH2 + N_WLIN;
    const size_t need = WS_WEIGHT_OFF + sizeof(__half) * nweights;

    if (ws_size >= need) {
        __half* hWih1 = (__half*)((char*)d_ws + WS_WEIGHT_OFF);
        __half* hWhh1 = hWih1 + N_WIH1;
        __half* hWih2 = hWhh1 + N_WHH1;
        __half* hWhh2 = hWih2 + N_WIH2;
        __half* hWlin = hWhh2 + N_WHH2;

        const float* srcs[5] = { Wih1, Whh1, Wih2, Whh2, Wlin };
        __half*      dsts[5] = { hWih1, hWhh1, hWih2, hWhh2, hWlin };
        const int    ns[5]   = { N_WIH1, N_WHH1, N_WIH2, N_WHH2, N_WLIN };
        for (int m = 0; m < 5; ++m) {
            int n4 = ns[m] / 4;
            convert_f16<<<(n4 + 255) / 256, 256, 0, stream>>>(srcs[m], dsts[m], n4);
        }

        const __half* cWih1 = hWih1; const __half* cWhh1 = hWhh1;
        const __half* cWih2 = hWih2; const __half* cWhh2 = hWhh2;
        const __half* cWlin = hWlin;
        void* args[] = {
            (void*)&x,
            (void*)&cWih1, (void*)&cWhh1, (void*)&bih1, (void*)&bhh1,
            (void*)&cWih2, (void*)&cWhh2, (void*)&bih2, (void*)&bhh2,
            (void*)&cWlin, (void*)&blin,
            (void*)&out, (void*)&bar, (void*)&h1buf, (void*)&h2buf
        };
        hipLaunchCooperativeKernel((const void*)lstm_resident, dim3(NWG), dim3(NTHR),
                                   args, 0, stream);
    } else {
        void* args[] = {
            (void*)&x,
            (void*)&Wih1, (void*)&Whh1, (void*)&bih1, (void*)&bhh1,
            (void*)&Wih2, (void*)&Whh2, (void*)&bih2, (void*)&bhh2,
            (void*)&Wlin, (void*)&blin,
            (void*)&out, (void*)&bar, (void*)&h1buf, (void*)&h2buf
        };
        hipLaunchCooperativeKernel((const void*)lstm_stream_f32, dim3(NWG), dim3(NTHR),
                                   args, 0, stream);
    }
}

// Round 2
// 76355.475 us; speedup vs baseline: 1.4687x; 1.4687x over previous
//
#include <hip/hip_runtime.h>
#include <hip/hip_fp16.h>

// LSTM_54537494725306: 2-layer LSTM, T=2048, D=512, H=2048, OUT=64, fp32 in/out.
// R4: fix R3's catastrophic spill. R3 asked for ~220 live VGPRs under a 128-reg
// cap (launch_bounds(512,2) pinned 4 waves/SIMD) -> per-step spill/fill around
// the grid barrier: WRITE_SIZE 165 GB, VALUBusy 4.4%, 112 ms.
// Changes:
//   * __launch_bounds__(512, 1): register cap >= 256 under either 2nd-arg
//     interpretation (waves/EU or blocks/CU).
//   * Whh1 moved ENTIRELY to LDS: 8 waves x 4 rows x 2048 fp16 = 128 KiB static
//     (proven size on gfx950; forces 1 WG/CU = 2 waves/SIMD, which is also the
//     occupancy that grants 256 VGPRs/wave).
//   * VGPR weight demand drops 176 -> 144 (Wih1 16 + Wih2 64 + Whh2 64), total
//     live ~200 < 256.
// Weights still fetched from HBM exactly once; per-step global traffic is only
// x/h vectors (L1-resident) + Wlin for the 64 y-waves.
// Math is bit-identical to R2/R3 (fp16 weights -> f32 cvt -> f32 fmaf, same order).

#define T_STEPS 2048
#define DIM_D   512
#define DIM_H   2048
#define DIM_OUT 64
#define NWG     256
#define NTHR    512

#define N_WIH1 (4 * DIM_H * DIM_D)   //  4,194,304
#define N_WHH1 (4 * DIM_H * DIM_H)   // 16,777,216
#define N_WIH2 (4 * DIM_H * DIM_H)
#define N_WHH2 (4 * DIM_H * DIM_H)
#define N_WLIN (DIM_OUT * DIM_H)     //    131,072
#define WS_WEIGHT_OFF 65536

__device__ __forceinline__ float sigf(float x)   { return 1.0f / (1.0f + __expf(-x)); }
__device__ __forceinline__ float tanh_f(float x) { return 1.0f - 2.0f / (__expf(2.0f * x) + 1.0f); }

__device__ __forceinline__ float wave_reduce(float v) {
#pragma unroll
    for (int off = 32; off > 0; off >>= 1) v += __shfl_xor(v, off, 64);
    return v;
}

struct F8 { float4 a, b; };

__device__ __forceinline__ F8 load8(const float* __restrict__ p, int e) {
    F8 r;
    const float4* q = (const float4*)(p + e);
    r.a = q[0]; r.b = q[1];
    return r;
}

__device__ __forceinline__ F8 cvt8(uint4 u) {
    float2 f0 = __half22float2(*(__half2*)&u.x);
    float2 f1 = __half22float2(*(__half2*)&u.y);
    float2 f2 = __half22float2(*(__half2*)&u.z);
    float2 f3 = __half22float2(*(__half2*)&u.w);
    F8 r;
    r.a = make_float4(f0.x, f0.y, f1.x, f1.y);
    r.b = make_float4(f2.x, f2.y, f3.x, f3.y);
    return r;
}

__device__ __forceinline__ F8 load8(const __half* __restrict__ p, int e) {
    uint4 u = *(const uint4*)(p + e);
    return cvt8(u);
}

__device__ __forceinline__ float dot8(const F8& v, const F8& w, float acc) {
    acc = fmaf(v.a.x, w.a.x, acc); acc = fmaf(v.a.y, w.a.y, acc);
    acc = fmaf(v.a.z, w.a.z, acc); acc = fmaf(v.a.w, w.a.w, acc);
    acc = fmaf(v.b.x, w.b.x, acc); acc = fmaf(v.b.y, w.b.y, acc);
    acc = fmaf(v.b.z, w.b.z, acc); acc = fmaf(v.b.w, w.b.w, acc);
    return acc;
}

// 4-row dot over K elements (fallback streaming path only).
template<int K, typename WT>
__device__ __forceinline__ void dot4(const float* __restrict__ v,
                                     const WT* __restrict__ w0, const WT* __restrict__ w1,
                                     const WT* __restrict__ w2, const WT* __restrict__ w3,
                                     int lane, float& a0, float& a1, float& a2, float& a3) {
#pragma unroll
    for (int i = 0; i < K / 512; ++i) {
        const int e = (lane + 64 * i) * 8;
        const F8 vv = load8(v, e);
        a0 = dot8(vv, load8(w0, e), a0);
        a1 = dot8(vv, load8(w1, e), a1);
        a2 = dot8(vv, load8(w2, e), a2);
        a3 = dot8(vv, load8(w3, e), a3);
    }
}

// Two-level sense-free barrier. Generation counter is the loop index p.
__device__ __forceinline__ void grid_barrier(int* bar, int wg, int g) {
    __syncthreads();
    if (threadIdx.x == 0) {
        const int grp = wg >> 5;
        int a = __hip_atomic_fetch_add(&bar[grp * 32], 1, __ATOMIC_ACQ_REL, __HIP_MEMORY_SCOPE_AGENT);
        if (a == 31) {
            int r = __hip_atomic_fetch_add(&bar[256], 1, __ATOMIC_ACQ_REL, __HIP_MEMORY_SCOPE_AGENT);
            if (r == 7) {
#pragma unroll
                for (int i = 0; i < 8; ++i)
                    __hip_atomic_store(&bar[i * 32], 0, __ATOMIC_RELAXED, __HIP_MEMORY_SCOPE_AGENT);
                __hip_atomic_store(&bar[256], 0, __ATOMIC_RELAXED, __HIP_MEMORY_SCOPE_AGENT);
                __hip_atomic_store(&bar[288], g + 1, __ATOMIC_RELEASE, __HIP_MEMORY_SCOPE_AGENT);
            }
        }
        while (__hip_atomic_load(&bar[288], __ATOMIC_RELAXED, __HIP_MEMORY_SCOPE_AGENT) <= g) {
            __builtin_amdgcn_s_sleep(2);
        }
        __builtin_amdgcn_fence(__ATOMIC_ACQUIRE, "agent");
    }
    __syncthreads();
}

__global__ void lstm_init(int* bar, float* h1buf, float* h2buf) {
    int i = threadIdx.x + blockIdx.x * blockDim.x;
    if (i < 512) bar[i] = 0;
    if (i < 2 * DIM_H) { h1buf[i] = 0.0f; h2buf[i] = 0.0f; }
}

// fp32 -> fp16 (RNE), 4 elements/thread.
__global__ void convert_f16(const float* __restrict__ src, __half* __restrict__ dst, int n4) {
    int i = threadIdx.x + blockIdx.x * blockDim.x;
    if (i < n4) {
        float4 f = ((const float4*)src)[i];
        __half2 h01 = __floats2half2_rn(f.x, f.y);
        __half2 h23 = __floats2half2_rn(f.z, f.w);
        uint2 o;
        o.x = *(unsigned int*)&h01;
        o.y = *(unsigned int*)&h23;
        ((uint2*)dst)[i] = o;
    }
}

// ---------------------------------------------------------------------------
// Main path: weights chip-resident.
//   per wave (unit u = wg*8+wave, rows u, H+u, 2H+u, 3H+u):
//     VGPR (packed fp16, uint4 = 8 elems): 144 regs
//       wI1[4]      Wih1 rows (K=512)          16 regs
//       wI2[4][4]   Wih2 rows (K=2048)         64 regs
//       wH2[4][4]   Whh2 rows (K=2048)         64 regs
//     LDS: Whh1 all 4 rows/wave: 8 waves * 4 * 2048 fp16 = 131072 B (128 KiB)
// ---------------------------------------------------------------------------
__global__ __launch_bounds__(NTHR, 1) void lstm_resident(
    const float* __restrict__ x,
    const __half* __restrict__ Wih1, const __half* __restrict__ Whh1,
    const float* __restrict__ bih1, const float* __restrict__ bhh1,
    const __half* __restrict__ Wih2, const __half* __restrict__ Whh2,
    const float* __restrict__ bih2, const float* __restrict__ bhh2,
    const __half* __restrict__ Wlin, const float* __restrict__ blin,
    float* __restrict__ out,
    int* bar, float* h1buf, float* h2buf)
{
    const int wg   = blockIdx.x;
    const int wave = threadIdx.x >> 6;
    const int lane = threadIdx.x & 63;
    const int unit = wg * 8 + wave;

    __shared__ uint4 ldsW[8][4][DIM_H / 8];   // 131072 bytes

    const int r0 = unit, r1 = DIM_H + unit, r2 = 2 * DIM_H + unit, r3 = 3 * DIM_H + unit;

    const float b1_0 = bih1[r0] + bhh1[r0];
    const float b1_1 = bih1[r1] + bhh1[r1];
    const float b1_2 = bih1[r2] + bhh1[r2];
    const float b1_3 = bih1[r3] + bhh1[r3];
    const float b2_0 = bih2[r0] + bhh2[r0];
    const float b2_1 = bih2[r1] + bhh2[r1];
    const float b2_2 = bih2[r2] + bhh2[r2];
    const float b2_3 = bih2[r3] + bhh2[r3];

    // ---------------- one-time weight residency ----------------
    uint4 wI1[4];
    uint4 wI2[4][4], wH2[4][4];
    {
        wI1[0] = ((const uint4*)(Wih1 + (size_t)r0 * DIM_D))[lane];
        wI1[1] = ((const uint4*)(Wih1 + (size_t)r1 * DIM_D))[lane];
        wI1[2] = ((const uint4*)(Wih1 + (size_t)r2 * DIM_D))[lane];
        wI1[3] = ((const uint4*)(Wih1 + (size_t)r3 * DIM_D))[lane];

        const uint4* pi0 = (const uint4*)(Wih2 + (size_t)r0 * DIM_H);
        const uint4* pi1 = (const uint4*)(Wih2 + (size_t)r1 * DIM_H);
        const uint4* pi2 = (const uint4*)(Wih2 + (size_t)r2 * DIM_H);
        const uint4* pi3 = (const uint4*)(Wih2 + (size_t)r3 * DIM_H);
        const uint4* ph0 = (const uint4*)(Whh2 + (size_t)r0 * DIM_H);
        const uint4* ph1 = (const uint4*)(Whh2 + (size_t)r1 * DIM_H);
        const uint4* ph2 = (const uint4*)(Whh2 + (size_t)r2 * DIM_H);
        const uint4* ph3 = (const uint4*)(Whh2 + (size_t)r3 * DIM_H);
#pragma unroll
        for (int i = 0; i < 4; ++i) {
            const int t = lane + 64 * i;
            wI2[0][i] = pi0[t]; wI2[1][i] = pi1[t];
            wI2[2][i] = pi2[t]; wI2[3][i] = pi3[t];
            wH2[0][i] = ph0[t]; wH2[1][i] = ph1[t];
            wH2[2][i] = ph2[t]; wH2[3][i] = ph3[t];
        }

        const uint4* q0 = (const uint4*)(Whh1 + (size_t)r0 * DIM_H);
        const uint4* q1 = (const uint4*)(Whh1 + (size_t)r1 * DIM_H);
        const uint4* q2 = (const uint4*)(Whh1 + (size_t)r2 * DIM_H);
        const uint4* q3 = (const uint4*)(Whh1 + (size_t)r3 * DIM_H);
#pragma unroll
        for (int i = 0; i < 4; ++i) {
            const int t = lane + 64 * i;
            ldsW[wave][0][t] = q0[t];
            ldsW[wave][1][t] = q1[t];
            ldsW[wave][2][t] = q2[t];
            ldsW[wave][3][t] = q3[t];
        }
    }
    __syncthreads();

    const bool  do_y = (wg < DIM_OUT) && (wave == 0);
    const float by   = (wg < DIM_OUT) ? blin[wg] : 0.0f;
    const __half* wy = Wlin + (size_t)(wg < DIM_OUT ? wg : 0) * DIM_H;

    float c1 = 0.0f, c2 = 0.0f;

    for (int p = 0; p < T_STEPS + 2; ++p) {
        const float* h1_prev  = h1buf + (size_t)((p + 1) & 1) * DIM_H;  // h1[p-1]
        float*       h1_cur   = h1buf + (size_t)(p & 1) * DIM_H;        // h1[p]
        const float* h2_prev2 = h2buf + (size_t)(p & 1) * DIM_H;        // h2[p-2]
        float*       h2_cur   = h2buf + (size_t)((p + 1) & 1) * DIM_H;  // h2[p-1]

        // ---------------- layer 1, step p ----------------
        if (p < T_STEPS) {
            float a0 = 0.f, a1 = 0.f, a2 = 0.f, a3 = 0.f;
            const F8 xv = load8(x + (size_t)p * DIM_D, lane * 8);
            a0 = dot8(xv, cvt8(wI1[0]), a0);
            a1 = dot8(xv, cvt8(wI1[1]), a1);
            a2 = dot8(xv, cvt8(wI1[2]), a2);
            a3 = dot8(xv, cvt8(wI1[3]), a3);
#pragma unroll
            for (int i = 0; i < 4; ++i) {
                const int t = lane + 64 * i;
                const F8 hv = load8(h1_prev, t * 8);
                a0 = dot8(hv, cvt8(ldsW[wave][0][t]), a0);
                a1 = dot8(hv, cvt8(ldsW[wave][1][t]), a1);
                a2 = dot8(hv, cvt8(ldsW[wave][2][t]), a2);
                a3 = dot8(hv, cvt8(ldsW[wave][3][t]), a3);
            }
            a0 = wave_reduce(a0); a1 = wave_reduce(a1);
            a2 = wave_reduce(a2); a3 = wave_reduce(a3);
            const float gi = sigf(a0 + b1_0);
            const float gf = sigf(a1 + b1_1);
            const float gg = tanh_f(a2 + b1_2);
            const float go = sigf(a3 + b1_3);
            c1 = fmaf(gf, c1, gi * gg);
            if (lane == 0) h1_cur[unit] = go * tanh_f(c1);
        }

        // ---------------- layer 2, step p-1 ----------------
        if (p >= 1 && p <= T_STEPS) {
            float a0 = 0.f, a1 = 0.f, a2 = 0.f, a3 = 0.f;
#pragma unroll
            for (int i = 0; i < 4; ++i) {
                const int t = lane + 64 * i;
                const F8 v = load8(h1_prev, t * 8);
                a0 = dot8(v, cvt8(wI2[0][i]), a0);
                a1 = dot8(v, cvt8(wI2[1][i]), a1);
                a2 = dot8(v, cvt8(wI2[2][i]), a2);
                a3 = dot8(v, cvt8(wI2[3][i]), a3);
            }
#pragma unroll
            for (int i = 0; i < 4; ++i) {
                const int t = lane + 64 * i;
                const F8 v = load8(h2_prev2, t * 8);
                a0 = dot8(v, cvt8(wH2[0][i]), a0);
                a1 = dot8(v, cvt8(wH2[1][i]), a1);
                a2 = dot8(v, cvt8(wH2[2][i]), a2);
                a3 = dot8(v, cvt8(wH2[3][i]), a3);
            }
            a0 = wave_reduce(a0); a1 = wave_reduce(a1);
            a2 = wave_reduce(a2); a3 = wave_reduce(a3);
            const float gi = sigf(a0 + b2_0);
            const float gf = sigf(a1 + b2_1);
            const float gg = tanh_f(a2 + b2_2);
            const float go = sigf(a3 + b2_3);
            c2 = fmaf(gf, c2, gi * gg);
            if (lane == 0) h2_cur[unit] = go * tanh_f(c2);
        }

        // ---------------- y, step p-2 ----------------
        if (do_y && p >= 2) {
            float a = 0.f;
#pragma unroll
            for (int i = 0; i < DIM_H / 512; ++i) {
                const int e = (lane + 64 * i) * 8;
                a = dot8(load8(h2_prev2, e), load8(wy, e), a);
            }
            a = wave_reduce(a);
            if (lane == 0) out[(size_t)(p - 2) * DIM_OUT + wg] = a + by;
        }

        grid_barrier(bar, wg, p);
    }
}

// ---------------------------------------------------------------------------
// Fallback: R2-style fp32 weight streaming (used only if workspace too small).
// ---------------------------------------------------------------------------
__global__ __launch_bounds__(NTHR, 2) void lstm_stream_f32(
    const float* __restrict__ x,
    const float* __restrict__ Wih1, const float* __restrict__ Whh1,
    const float* __restrict__ bih1, const float* __restrict__ bhh1,
    const float* __restrict__ Wih2, const float* __restrict__ Whh2,
    const float* __restrict__ bih2, const float* __restrict__ bhh2,
    const float* __restrict__ Wlin, const float* __restrict__ blin,
    float* __restrict__ out,
    int* bar, float* h1buf, float* h2buf)
{
    const int wg   = blockIdx.x;
    const int wave = threadIdx.x >> 6;
    const int lane = threadIdx.x & 63;
    const int unit = wg * 8 + wave;

    const int r0 = unit, r1 = DIM_H + unit, r2 = 2 * DIM_H + unit, r3 = 3 * DIM_H + unit;
    const float b1_0 = bih1[r0] + bhh1[r0];
    const float b1_1 = bih1[r1] + bhh1[r1];
    const float b1_2 = bih1[r2] + bhh1[r2];
    const float b1_3 = bih1[r3] + bhh1[r3];
    const float b2_0 = bih2[r0] + bhh2[r0];
    const float b2_1 = bih2[r1] + bhh2[r1];
    const float b2_2 = bih2[r2] + bhh2[r2];
    const float b2_3 = bih2[r3] + bhh2[r3];

    const float* wi1_0 = Wih1 + (size_t)r0 * DIM_D;
    const float* wi1_1 = Wih1 + (size_t)r1 * DIM_D;
    const float* wi1_2 = Wih1 + (size_t)r2 * DIM_D;
    const float* wi1_3 = Wih1 + (size_t)r3 * DIM_D;
    const float* wh1_0 = Whh1 + (size_t)r0 * DIM_H;
    const float* wh1_1 = Whh1 + (size_t)r1 * DIM_H;
    const float* wh1_2 = Whh1 + (size_t)r2 * DIM_H;
    const float* wh1_3 = Whh1 + (size_t)r3 * DIM_H;
    const float* wi2_0 = Wih2 + (size_t)r0 * DIM_H;
    const float* wi2_1 = Wih2 + (size_t)r1 * DIM_H;
    const float* wi2_2 = Wih2 + (size_t)r2 * DIM_H;
    const float* wi2_3 = Wih2 + (size_t)r3 * DIM_H;
    const float* wh2_0 = Whh2 + (size_t)r0 * DIM_H;
    const float* wh2_1 = Whh2 + (size_t)r1 * DIM_H;
    const float* wh2_2 = Whh2 + (size_t)r2 * DIM_H;
    const float* wh2_3 = Whh2 + (size_t)r3 * DIM_H;

    const bool  do_y = (wg < DIM_OUT) && (wave == 0);
    const float by   = (wg < DIM_OUT) ? blin[wg] : 0.0f;
    const float* wy  = Wlin + (size_t)(wg < DIM_OUT ? wg : 0) * DIM_H;

    float c1 = 0.0f, c2 = 0.0f;

    for (int p = 0; p < T_STEPS + 2; ++p) {
        const float* h1_prev  = h1buf + (size_t)((p + 1) & 1) * DIM_H;
        float*       h1_cur   = h1buf + (size_t)(p & 1) * DIM_H;
        const float* h2_prev2 = h2buf + (size_t)(p & 1) * DIM_H;
        float*       h2_cur   = h2buf + (size_t)((p + 1) & 1) * DIM_H;

        if (p < T_STEPS) {
            float a0 = 0.f, a1 = 0.f, a2 = 0.f, a3 = 0.f;
            dot4<DIM_D>(x + (size_t)p * DIM_D, wi1_0, wi1_1, wi1_2, wi1_3, lane, a0, a1, a2, a3);
            dot4<DIM_H>(h1_prev, wh1_0, wh1_1, wh1_2, wh1_3, lane, a0, a1, a2, a3);
            a0 = wave_reduce(a0); a1 = wave_reduce(a1);
            a2 = wave_reduce(a2); a3 = wave_reduce(a3);
            const float gi = sigf(a0 + b1_0);
            const float gf = sigf(a1 + b1_1);
            const float gg = tanh_f(a2 + b1_2);
            const float go = sigf(a3 + b1_3);
            c1 = fmaf(gf, c1, gi * gg);
            if (lane == 0) h1_cur[unit] = go * tanh_f(c1);
        }

        if (p >= 1 && p <= T_STEPS) {
            float a0 = 0.f, a1 = 0.f, a2 = 0.f, a3 = 0.f;
            dot4<DIM_H>(h1_prev,  wi2_0, wi2_1, wi2_2, wi2_3, lane, a0, a1, a2, a3);
            dot4<DIM_H>(h2_prev2, wh2_0, wh2_1, wh2_2, wh2_3, lane, a0, a1, a2, a3);
            a0 = wave_reduce(a0); a1 = wave_reduce(a1);
            a2 = wave_reduce(a2); a3 = wave_reduce(a3);
            const float gi = sigf(a0 + b2_0);
            const float gf = sigf(a1 + b2_1);
            const float gg = tanh_f(a2 + b2_2);
            const float go = sigf(a3 + b2_3);
            c2 = fmaf(gf, c2, gi * gg);
            if (lane == 0) h2_cur[unit] = go * tanh_f(c2);
        }

        if (do_y && p >= 2) {
            float a = 0.f;
#pragma unroll
            for (int i = 0; i < DIM_H / 512; ++i) {
                const int e = (lane + 64 * i) * 8;
                a = dot8(load8(h2_prev2, e), load8(wy, e), a);
            }
            a = wave_reduce(a);
            if (lane == 0) out[(size_t)(p - 2) * DIM_OUT + wg] = a + by;
        }

        grid_barrier(bar, wg, p);
    }
}

extern "C" void kernel_launch(void* const* d_in, const int* in_sizes, int n_in,
                              void* d_out, int out_size, void* d_ws, size_t ws_size,
                              hipStream_t stream) {
    const float* x    = (const float*)d_in[0];
    const float* Wih1 = (const float*)d_in[1];
    const float* Whh1 = (const float*)d_in[2];
    const float* bih1 = (const float*)d_in[3];
    const float* bhh1 = (const float*)d_in[4];
    const float* Wih2 = (const float*)d_in[5];
    const float* Whh2 = (const float*)d_in[6];
    const float* bih2 = (const float*)d_in[7];
    const float* bhh2 = (const float*)d_in[8];
    const float* Wlin = (const float*)d_in[9];
    const float* blin = (const float*)d_in[10];
    float* out = (float*)d_out;

    int*   bar   = (int*)d_ws;
    float* h1buf = (float*)((char*)d_ws + 4096);
    float* h2buf = h1buf + 2 * DIM_H;

    lstm_init<<<16, 256, 0, stream>>>(bar, h1buf, h2buf);

    const size_t nweights = (size_t)N_WIH1 + N_WHH1 + N_WIH2 + N_WHH2 + N_WLIN;
    const size_t need = WS_WEIGHT_OFF + sizeof(__half) * nweights;

    if (ws_size >= need) {
        __half* hWih1 = (__half*)((char*)d_ws + WS_WEIGHT_OFF);
        __half* hWhh1 = hWih1 + N_WIH1;
        __half* hWih2 = hWhh1 + N_WHH1;
        __half* hWhh2 = hWih2 + N_WIH2;
        __half* hWlin = hWhh2 + N_WHH2;

        const float* srcs[5] = { Wih1, Whh1, Wih2, Whh2, Wlin };
        __half*      dsts[5] = { hWih1, hWhh1, hWih2, hWhh2, hWlin };
        const int    ns[5]   = { N_WIH1, N_WHH1, N_WIH2, N_WHH2, N_WLIN };
        for (int m = 0; m < 5; ++m) {
            int n4 = ns[m] / 4;
            convert_f16<<<(n4 + 255) / 256, 256, 0, stream>>>(srcs[m], dsts[m], n4);
        }

        const __half* cWih1 = hWih1; const __half* cWhh1 = hWhh1;
        const __half* cWih2 = hWih2; const __half* cWhh2 = hWhh2;
        const __half* cWlin = hWlin;
        void* args[] = {
            (void*)&x,
            (void*)&cWih1, (void*)&cWhh1, (void*)&bih1, (void*)&bhh1,
            (void*)&cWih2, (void*)&cWhh2, (void*)&bih2, (void*)&bhh2,
            (void*)&cWlin, (void*)&blin,
            (void*)&out, (void*)&bar, (void*)&h1buf, (void*)&h2buf
        };
        hipLaunchCooperativeKernel((const void*)lstm_resident, dim3(NWG), dim3(NTHR),
                                   args, 0, stream);
    } else {
        void* args[] = {
            (void*)&x,
            (void*)&Wih1, (void*)&Whh1, (void*)&bih1, (void*)&bhh1,
            (void*)&Wih2, (void*)&Whh2, (void*)&bih2, (void*)&bhh2,
            (void*)&Wlin, (void*)&blin,
            (void*)&out, (void*)&bar, (void*)&h1buf, (void*)&h2buf
        };
        hipLaunchCooperativeKernel((const void*)lstm_stream_f32, dim3(NWG), dim3(NTHR),
                                   args, 0, stream);
    }
}

// Round 3
// 43369.965 us; speedup vs baseline: 2.5857x; 1.7606x over previous
//
#include <hip/hip_runtime.h>
#include <hip/hip_fp16.h>

// LSTM_54537494725306: 2-layer LSTM, T=2048, D=512, H=2048, OUT=64, fp32 in/out.
// R5: kill the spill for real. R3/R4 both got a 128-VGPR cap: launch_bounds'
// 2nd arg only sets MIN waves/EU; the LLVM allocator still TARGETS 4 waves/EU
// and spills to get there (WRITE_SIZE 117 GB = 57 MB/step scratch stores).
// Fix: amdgpu_waves_per_eu(2,2) — max=2 tells the allocator occupancy >2
// waves/EU is impossible (LDS already forces 1 WG/CU), so it may use up to
// 256 VGPRs. Also moved Wih1 into LDS: total LDS = 160 KiB (exactly the
// gfx950 pool), register weight demand 144 -> 128 (Wih2 64 + Whh2 64).
// Weights fetched from HBM exactly once; per-step global traffic is only
// x/h vectors (L1/L2-resident) + Wlin for the 64 y-waves.
// Math is bit-identical to R2-R4 (fp16 weights -> f32 cvt -> f32 fmaf, same order).

#define T_STEPS 2048
#define DIM_D   512
#define DIM_H   2048
#define DIM_OUT 64
#define NWG     256
#define NTHR    512

#define N_WIH1 (4 * DIM_H * DIM_D)   //  4,194,304
#define N_WHH1 (4 * DIM_H * DIM_H)   // 16,777,216
#define N_WIH2 (4 * DIM_H * DIM_H)
#define N_WHH2 (4 * DIM_H * DIM_H)
#define N_WLIN (DIM_OUT * DIM_H)     //    131,072
#define WS_WEIGHT_OFF 65536

__device__ __forceinline__ float sigf(float x)   { return 1.0f / (1.0f + __expf(-x)); }
__device__ __forceinline__ float tanh_f(float x) { return 1.0f - 2.0f / (__expf(2.0f * x) + 1.0f); }

__device__ __forceinline__ float wave_reduce(float v) {
#pragma unroll
    for (int off = 32; off > 0; off >>= 1) v += __shfl_xor(v, off, 64);
    return v;
}

struct F8 { float4 a, b; };

__device__ __forceinline__ F8 load8(const float* __restrict__ p, int e) {
    F8 r;
    const float4* q = (const float4*)(p + e);
    r.a = q[0]; r.b = q[1];
    return r;
}

__device__ __forceinline__ F8 cvt8(uint4 u) {
    float2 f0 = __half22float2(*(__half2*)&u.x);
    float2 f1 = __half22float2(*(__half2*)&u.y);
    float2 f2 = __half22float2(*(__half2*)&u.z);
    float2 f3 = __half22float2(*(__half2*)&u.w);
    F8 r;
    r.a = make_float4(f0.x, f0.y, f1.x, f1.y);
    r.b = make_float4(f2.x, f2.y, f3.x, f3.y);
    return r;
}

__device__ __forceinline__ F8 load8(const __half* __restrict__ p, int e) {
    uint4 u = *(const uint4*)(p + e);
    return cvt8(u);
}

__device__ __forceinline__ float dot8(const F8& v, const F8& w, float acc) {
    acc = fmaf(v.a.x, w.a.x, acc); acc = fmaf(v.a.y, w.a.y, acc);
    acc = fmaf(v.a.z, w.a.z, acc); acc = fmaf(v.a.w, w.a.w, acc);
    acc = fmaf(v.b.x, w.b.x, acc); acc = fmaf(v.b.y, w.b.y, acc);
    acc = fmaf(v.b.z, w.b.z, acc); acc = fmaf(v.b.w, w.b.w, acc);
    return acc;
}

// 4-row dot over K elements (fallback streaming path only).
template<int K, typename WT>
__device__ __forceinline__ void dot4(const float* __restrict__ v,
                                     const WT* __restrict__ w0, const WT* __restrict__ w1,
                                     const WT* __restrict__ w2, const WT* __restrict__ w3,
                                     int lane, float& a0, float& a1, float& a2, float& a3) {
#pragma unroll
    for (int i = 0; i < K / 512; ++i) {
        const int e = (lane + 64 * i) * 8;
        const F8 vv = load8(v, e);
        a0 = dot8(vv, load8(w0, e), a0);
        a1 = dot8(vv, load8(w1, e), a1);
        a2 = dot8(vv, load8(w2, e), a2);
        a3 = dot8(vv, load8(w3, e), a3);
    }
}

// Two-level sense-free barrier. Generation counter is the loop index p.
__device__ __forceinline__ void grid_barrier(int* bar, int wg, int g) {
    __syncthreads();
    if (threadIdx.x == 0) {
        const int grp = wg >> 5;
        int a = __hip_atomic_fetch_add(&bar[grp * 32], 1, __ATOMIC_ACQ_REL, __HIP_MEMORY_SCOPE_AGENT);
        if (a == 31) {
            int r = __hip_atomic_fetch_add(&bar[256], 1, __ATOMIC_ACQ_REL, __HIP_MEMORY_SCOPE_AGENT);
            if (r == 7) {
#pragma unroll
                for (int i = 0; i < 8; ++i)
                    __hip_atomic_store(&bar[i * 32], 0, __ATOMIC_RELAXED, __HIP_MEMORY_SCOPE_AGENT);
                __hip_atomic_store(&bar[256], 0, __ATOMIC_RELAXED, __HIP_MEMORY_SCOPE_AGENT);
                __hip_atomic_store(&bar[288], g + 1, __ATOMIC_RELEASE, __HIP_MEMORY_SCOPE_AGENT);
            }
        }
        while (__hip_atomic_load(&bar[288], __ATOMIC_RELAXED, __HIP_MEMORY_SCOPE_AGENT) <= g) {
            __builtin_amdgcn_s_sleep(2);
        }
        __builtin_amdgcn_fence(__ATOMIC_ACQUIRE, "agent");
    }
    __syncthreads();
}

__global__ void lstm_init(int* bar, float* h1buf, float* h2buf) {
    int i = threadIdx.x + blockIdx.x * blockDim.x;
    if (i < 512) bar[i] = 0;
    if (i < 2 * DIM_H) { h1buf[i] = 0.0f; h2buf[i] = 0.0f; }
}

// fp32 -> fp16 (RNE), 4 elements/thread.
__global__ void convert_f16(const float* __restrict__ src, __half* __restrict__ dst, int n4) {
    int i = threadIdx.x + blockIdx.x * blockDim.x;
    if (i < n4) {
        float4 f = ((const float4*)src)[i];
        __half2 h01 = __floats2half2_rn(f.x, f.y);
        __half2 h23 = __floats2half2_rn(f.z, f.w);
        uint2 o;
        o.x = *(unsigned int*)&h01;
        o.y = *(unsigned int*)&h23;
        ((uint2*)dst)[i] = o;
    }
}

// ---------------------------------------------------------------------------
// Main path: weights chip-resident.
//   per wave (unit u = wg*8+wave, rows u, H+u, 2H+u, 3H+u):
//     VGPR (packed fp16, uint4 = 8 elems = 4 regs): 128 regs of weights
//       wI2[4][4]   Wih2 rows (K=2048)         64 regs
//       wH2[4][4]   Whh2 rows (K=2048)         64 regs
//     LDS (160 KiB total = full gfx950 pool):
//       ldsW: Whh1 4 rows/wave: 8*4*2048 fp16 = 131072 B
//       ldsX: Wih1 4 rows/wave: 8*4* 512 fp16 =  32768 B
// ---------------------------------------------------------------------------
__global__ __attribute__((amdgpu_flat_work_group_size(NTHR, NTHR), amdgpu_waves_per_eu(2, 2)))
void lstm_resident(
    const float* __restrict__ x,
    const __half* __restrict__ Wih1, const __half* __restrict__ Whh1,
    const float* __restrict__ bih1, const float* __restrict__ bhh1,
    const __half* __restrict__ Wih2, const __half* __restrict__ Whh2,
    const float* __restrict__ bih2, const float* __restrict__ bhh2,
    const __half* __restrict__ Wlin, const float* __restrict__ blin,
    float* __restrict__ out,
    int* bar, float* h1buf, float* h2buf)
{
    const int wg   = blockIdx.x;
    const int wave = threadIdx.x >> 6;
    const int lane = threadIdx.x & 63;
    const int unit = wg * 8 + wave;

    __shared__ uint4 ldsW[8][4][DIM_H / 8];   // 131072 bytes (Whh1)
    __shared__ uint4 ldsX[8][4][DIM_D / 8];   //  32768 bytes (Wih1)

    const int r0 = unit, r1 = DIM_H + unit, r2 = 2 * DIM_H + unit, r3 = 3 * DIM_H + unit;

    const float b1_0 = bih1[r0] + bhh1[r0];
    const float b1_1 = bih1[r1] + bhh1[r1];
    const float b1_2 = bih1[r2] + bhh1[r2];
    const float b1_3 = bih1[r3] + bhh1[r3];
    const float b2_0 = bih2[r0] + bhh2[r0];
    const float b2_1 = bih2[r1] + bhh2[r1];
    const float b2_2 = bih2[r2] + bhh2[r2];
    const float b2_3 = bih2[r3] + bhh2[r3];

    // ---------------- one-time weight residency ----------------
    uint4 wI2[4][4], wH2[4][4];
    {
        const uint4* pi0 = (const uint4*)(Wih2 + (size_t)r0 * DIM_H);
        const uint4* pi1 = (const uint4*)(Wih2 + (size_t)r1 * DIM_H);
        const uint4* pi2 = (const uint4*)(Wih2 + (size_t)r2 * DIM_H);
        const uint4* pi3 = (const uint4*)(Wih2 + (size_t)r3 * DIM_H);
        const uint4* ph0 = (const uint4*)(Whh2 + (size_t)r0 * DIM_H);
        const uint4* ph1 = (const uint4*)(Whh2 + (size_t)r1 * DIM_H);
        const uint4* ph2 = (const uint4*)(Whh2 + (size_t)r2 * DIM_H);
        const uint4* ph3 = (const uint4*)(Whh2 + (size_t)r3 * DIM_H);
#pragma unroll
        for (int i = 0; i < 4; ++i) {
            const int t = lane + 64 * i;
            wI2[0][i] = pi0[t]; wI2[1][i] = pi1[t];
            wI2[2][i] = pi2[t]; wI2[3][i] = pi3[t];
            wH2[0][i] = ph0[t]; wH2[1][i] = ph1[t];
            wH2[2][i] = ph2[t]; wH2[3][i] = ph3[t];
        }

        const uint4* q0 = (const uint4*)(Whh1 + (size_t)r0 * DIM_H);
        const uint4* q1 = (const uint4*)(Whh1 + (size_t)r1 * DIM_H);
        const uint4* q2 = (const uint4*)(Whh1 + (size_t)r2 * DIM_H);
        const uint4* q3 = (const uint4*)(Whh1 + (size_t)r3 * DIM_H);
#pragma unroll
        for (int i = 0; i < 4; ++i) {
            const int t = lane + 64 * i;
            ldsW[wave][0][t] = q0[t];
            ldsW[wave][1][t] = q1[t];
            ldsW[wave][2][t] = q2[t];
            ldsW[wave][3][t] = q3[t];
        }

        ldsX[wave][0][lane] = ((const uint4*)(Wih1 + (size_t)r0 * DIM_D))[lane];
        ldsX[wave][1][lane] = ((const uint4*)(Wih1 + (size_t)r1 * DIM_D))[lane];
        ldsX[wave][2][lane] = ((const uint4*)(Wih1 + (size_t)r2 * DIM_D))[lane];
        ldsX[wave][3][lane] = ((const uint4*)(Wih1 + (size_t)r3 * DIM_D))[lane];
    }
    __syncthreads();

    const bool  do_y = (wg < DIM_OUT) && (wave == 0);
    const float by   = (wg < DIM_OUT) ? blin[wg] : 0.0f;
    const __half* wy = Wlin + (size_t)(wg < DIM_OUT ? wg : 0) * DIM_H;

    float c1 = 0.0f, c2 = 0.0f;

    for (int p = 0; p < T_STEPS + 2; ++p) {
        const float* h1_prev  = h1buf + (size_t)((p + 1) & 1) * DIM_H;  // h1[p-1]
        float*       h1_cur   = h1buf + (size_t)(p & 1) * DIM_H;        // h1[p]
        const float* h2_prev2 = h2buf + (size_t)(p & 1) * DIM_H;        // h2[p-2]
        float*       h2_cur   = h2buf + (size_t)((p + 1) & 1) * DIM_H;  // h2[p-1]

        // ---------------- layer 1, step p ----------------
        if (p < T_STEPS) {
            float a0 = 0.f, a1 = 0.f, a2 = 0.f, a3 = 0.f;
            const F8 xv = load8(x + (size_t)p * DIM_D, lane * 8);
            a0 = dot8(xv, cvt8(ldsX[wave][0][lane]), a0);
            a1 = dot8(xv, cvt8(ldsX[wave][1][lane]), a1);
            a2 = dot8(xv, cvt8(ldsX[wave][2][lane]), a2);
            a3 = dot8(xv, cvt8(ldsX[wave][3][lane]), a3);
#pragma unroll
            for (int i = 0; i < 4; ++i) {
                const int t = lane + 64 * i;
                const F8 hv = load8(h1_prev, t * 8);
                a0 = dot8(hv, cvt8(ldsW[wave][0][t]), a0);
                a1 = dot8(hv, cvt8(ldsW[wave][1][t]), a1);
                a2 = dot8(hv, cvt8(ldsW[wave][2][t]), a2);
                a3 = dot8(hv, cvt8(ldsW[wave][3][t]), a3);
            }
            a0 = wave_reduce(a0); a1 = wave_reduce(a1);
            a2 = wave_reduce(a2); a3 = wave_reduce(a3);
            const float gi = sigf(a0 + b1_0);
            const float gf = sigf(a1 + b1_1);
            const float gg = tanh_f(a2 + b1_2);
            const float go = sigf(a3 + b1_3);
            c1 = fmaf(gf, c1, gi * gg);
            if (lane == 0) h1_cur[unit] = go * tanh_f(c1);
        }

        // ---------------- layer 2, step p-1 ----------------
        if (p >= 1 && p <= T_STEPS) {
            float a0 = 0.f, a1 = 0.f, a2 = 0.f, a3 = 0.f;
#pragma unroll
            for (int i = 0; i < 4; ++i) {
                const int t = lane + 64 * i;
                const F8 v = load8(h1_prev, t * 8);
                a0 = dot8(v, cvt8(wI2[0][i]), a0);
                a1 = dot8(v, cvt8(wI2[1][i]), a1);
                a2 = dot8(v, cvt8(wI2[2][i]), a2);
                a3 = dot8(v, cvt8(wI2[3][i]), a3);
            }
#pragma unroll
            for (int i = 0; i < 4; ++i) {
                const int t = lane + 64 * i;
                const F8 v = load8(h2_prev2, t * 8);
                a0 = dot8(v, cvt8(wH2[0][i]), a0);
                a1 = dot8(v, cvt8(wH2[1][i]), a1);
                a2 = dot8(v, cvt8(wH2[2][i]), a2);
                a3 = dot8(v, cvt8(wH2[3][i]), a3);
            }
            a0 = wave_reduce(a0); a1 = wave_reduce(a1);
            a2 = wave_reduce(a2); a3 = wave_reduce(a3);
            const float gi = sigf(a0 + b2_0);
            const float gf = sigf(a1 + b2_1);
            const float gg = tanh_f(a2 + b2_2);
            const float go = sigf(a3 + b2_3);
            c2 = fmaf(gf, c2, gi * gg);
            if (lane == 0) h2_cur[unit] = go * tanh_f(c2);
        }

        // ---------------- y, step p-2 ----------------
        if (do_y && p >= 2) {
            float a = 0.f;
#pragma unroll
            for (int i = 0; i < DIM_H / 512; ++i) {
                const int e = (lane + 64 * i) * 8;
                a = dot8(load8(h2_prev2, e), load8(wy, e), a);
            }
            a = wave_reduce(a);
            if (lane == 0) out[(size_t)(p - 2) * DIM_OUT + wg] = a + by;
        }

        grid_barrier(bar, wg, p);
    }
}

// ---------------------------------------------------------------------------
// Fallback: R2-style fp32 weight streaming (used only if workspace too small).
// ---------------------------------------------------------------------------
__global__ __launch_bounds__(NTHR, 2) void lstm_stream_f32(
    const float* __restrict__ x,
    const float* __restrict__ Wih1, const float* __restrict__ Whh1,
    const float* __restrict__ bih1, const float* __restrict__ bhh1,
    const float* __restrict__ Wih2, const float* __restrict__ Whh2,
    const float* __restrict__ bih2, const float* __restrict__ bhh2,
    const float* __restrict__ Wlin, const float* __restrict__ blin,
    float* __restrict__ out,
    int* bar, float* h1buf, float* h2buf)
{
    const int wg   = blockIdx.x;
    const int wave = threadIdx.x >> 6;
    const int lane = threadIdx.x & 63;
    const int unit = wg * 8 + wave;

    const int r0 = unit, r1 = DIM_H + unit, r2 = 2 * DIM_H + unit, r3 = 3 * DIM_H + unit;
    const float b1_0 = bih1[r0] + bhh1[r0];
    const float b1_1 = bih1[r1] + bhh1[r1];
    const float b1_2 = bih1[r2] + bhh1[r2];
    const float b1_3 = bih1[r3] + bhh1[r3];
    const float b2_0 = bih2[r0] + bhh2[r0];
    const float b2_1 = bih2[r1] + bhh2[r1];
    const float b2_2 = bih2[r2] + bhh2[r2];
    const float b2_3 = bih2[r3] + bhh2[r3];

    const float* wi1_0 = Wih1 + (size_t)r0 * DIM_D;
    const float* wi1_1 = Wih1 + (size_t)r1 * DIM_D;
    const float* wi1_2 = Wih1 + (size_t)r2 * DIM_D;
    const float* wi1_3 = Wih1 + (size_t)r3 * DIM_D;
    const float* wh1_0 = Whh1 + (size_t)r0 * DIM_H;
    const float* wh1_1 = Whh1 + (size_t)r1 * DIM_H;
    const float* wh1_2 = Whh1 + (size_t)r2 * DIM_H;
    const float* wh1_3 = Whh1 + (size_t)r3 * DIM_H;
    const float* wi2_0 = Wih2 + (size_t)r0 * DIM_H;
    const float* wi2_1 = Wih2 + (size_t)r1 * DIM_H;
    const float* wi2_2 = Wih2 + (size_t)r2 * DIM_H;
    const float* wi2_3 = Wih2 + (size_t)r3 * DIM_H;
    const float* wh2_0 = Whh2 + (size_t)r0 * DIM_H;
    const float* wh2_1 = Whh2 + (size_t)r1 * DIM_H;
    const float* wh2_2 = Whh2 + (size_t)r2 * DIM_H;
    const float* wh2_3 = Whh2 + (size_t)r3 * DIM_H;

    const bool  do_y = (wg < DIM_OUT) && (wave == 0);
    const float by   = (wg < DIM_OUT) ? blin[wg] : 0.0f;
    const float* wy  = Wlin + (size_t)(wg < DIM_OUT ? wg : 0) * DIM_H;

    float c1 = 0.0f, c2 = 0.0f;

    for (int p = 0; p < T_STEPS + 2; ++p) {
        const float* h1_prev  = h1buf + (size_t)((p + 1) & 1) * DIM_H;
        float*       h1_cur   = h1buf + (size_t)(p & 1) * DIM_H;
        const float* h2_prev2 = h2buf + (size_t)(p & 1) * DIM_H;
        float*       h2_cur   = h2buf + (size_t)((p + 1) & 1) * DIM_H;

        if (p < T_STEPS) {
            float a0 = 0.f, a1 = 0.f, a2 = 0.f, a3 = 0.f;
            dot4<DIM_D>(x + (size_t)p * DIM_D, wi1_0, wi1_1, wi1_2, wi1_3, lane, a0, a1, a2, a3);
            dot4<DIM_H>(h1_prev, wh1_0, wh1_1, wh1_2, wh1_3, lane, a0, a1, a2, a3);
            a0 = wave_reduce(a0); a1 = wave_reduce(a1);
            a2 = wave_reduce(a2); a3 = wave_reduce(a3);
            const float gi = sigf(a0 + b1_0);
            const float gf = sigf(a1 + b1_1);
            const float gg = tanh_f(a2 + b1_2);
            const float go = sigf(a3 + b1_3);
            c1 = fmaf(gf, c1, gi * gg);
            if (lane == 0) h1_cur[unit] = go * tanh_f(c1);
        }

        if (p >= 1 && p <= T_STEPS) {
            float a0 = 0.f, a1 = 0.f, a2 = 0.f, a3 = 0.f;
            dot4<DIM_H>(h1_prev,  wi2_0, wi2_1, wi2_2, wi2_3, lane, a0, a1, a2, a3);
            dot4<DIM_H>(h2_prev2, wh2_0, wh2_1, wh2_2, wh2_3, lane, a0, a1, a2, a3);
            a0 = wave_reduce(a0); a1 = wave_reduce(a1);
            a2 = wave_reduce(a2); a3 = wave_reduce(a3);
            const float gi = sigf(a0 + b2_0);
            const float gf = sigf(a1 + b2_1);
            const float gg = tanh_f(a2 + b2_2);
            const float go = sigf(a3 + b2_3);
            c2 = fmaf(gf, c2, gi * gg);
            if (lane == 0) h2_cur[unit] = go * tanh_f(c2);
        }

        if (do_y && p >= 2) {
            float a = 0.f;
#pragma unroll
            for (int i = 0; i < DIM_H / 512; ++i) {
                const int e = (lane + 64 * i) * 8;
                a = dot8(load8(h2_prev2, e), load8(wy, e), a);
            }
            a = wave_reduce(a);
            if (lane == 0) out[(size_t)(p - 2) * DIM_OUT + wg] = a + by;
        }

        grid_barrier(bar, wg, p);
    }
}

extern "C" void kernel_launch(void* const* d_in, const int* in_sizes, int n_in,
                              void* d_out, int out_size, void* d_ws, size_t ws_size,
                              hipStream_t stream) {
    const float* x    = (const float*)d_in[0];
    const float* Wih1 = (const float*)d_in[1];
    const float* Whh1 = (const float*)d_in[2];
    const float* bih1 = (const float*)d_in[3];
    const float* bhh1 = (const float*)d_in[4];
    const float* Wih2 = (const float*)d_in[5];
    const float* Whh2 = (const float*)d_in[6];
    const float* bih2 = (const float*)d_in[7];
    const float* bhh2 = (const float*)d_in[8];
    const float* Wlin = (const float*)d_in[9];
    const float* blin = (const float*)d_in[10];
    float* out = (float*)d_out;

    int*   bar   = (int*)d_ws;
    float* h1buf = (float*)((char*)d_ws + 4096);
    float* h2buf = h1buf + 2 * DIM_H;

    lstm_init<<<16, 256, 0, stream>>>(bar, h1buf, h2buf);

    const size_t nweights = (size_t)N_WIH1 + N_WHH1 + N_WIH2 + N_WHH2 + N_WLIN;
    const size_t need = WS_WEIGHT_OFF + sizeof(__half) * nweights;

    if (ws_size >= need) {
        __half* hWih1 = (__half*)((char*)d_ws + WS_WEIGHT_OFF);
        __half* hWhh1 = hWih1 + N_WIH1;
        __half* hWih2 = hWhh1 + N_WHH1;
        __half* hWhh2 = hWih2 + N_WIH2;
        __half* hWlin = hWhh2 + N_WHH2;

        const float* srcs[5] = { Wih1, Whh1, Wih2, Whh2, Wlin };
        __half*      dsts[5] = { hWih1, hWhh1, hWih2, hWhh2, hWlin };
        const int    ns[5]   = { N_WIH1, N_WHH1, N_WIH2, N_WHH2, N_WLIN };
        for (int m = 0; m < 5; ++m) {
            int n4 = ns[m] / 4;
            convert_f16<<<(n4 + 255) / 256, 256, 0, stream>>>(srcs[m], dsts[m], n4);
        }

        const __half* cWih1 = hWih1; const __half* cWhh1 = hWhh1;
        const __half* cWih2 = hWih2; const __half* cWhh2 = hWhh2;
        const __half* cWlin = hWlin;
        void* args[] = {
            (void*)&x,
            (void*)&cWih1, (void*)&cWhh1, (void*)&bih1, (void*)&bhh1,
            (void*)&cWih2, (void*)&cWhh2, (void*)&bih2, (void*)&bhh2,
            (void*)&cWlin, (void*)&blin,
            (void*)&out, (void*)&bar, (void*)&h1buf, (void*)&h2buf
        };
        hipLaunchCooperativeKernel((const void*)lstm_resident, dim3(NWG), dim3(NTHR),
                                   args, 0, stream);
    } else {
        void* args[] = {
            (void*)&x,
            (void*)&Wih1, (void*)&Whh1, (void*)&bih1, (void*)&bhh1,
            (void*)&Wih2, (void*)&Whh2, (void*)&bih2, (void*)&bhh2,
            (void*)&Wlin, (void*)&blin,
            (void*)&out, (void*)&bar, (void*)&h1buf, (void*)&h2buf
        };
        hipLaunchCooperativeKernel((const void*)lstm_stream_f32, dim3(NWG), dim3(NTHR),
                                   args, 0, stream);
    }
}